// Round 11
// baseline (389.613 us; speedup 1.0000x reference)
//
#include <hip/hip_runtime.h>
#include <hip/hip_bf16.h>

typedef __hip_bfloat16 bf16;
typedef __attribute__((ext_vector_type(8))) short bf16x8v;
typedef __attribute__((ext_vector_type(4))) float f32x4;

namespace {
constexpr int B_  = 2;
constexpr int C_  = 192;
constexpr int HW_ = 128 * 128;   // 16384
constexpr int C2_ = 384;
}

static __device__ __forceinline__ float fb(bf16 v) { return __bfloat162float(v); }
static __device__ __forceinline__ bf16 tob(float v) { return __float2bfloat16(v); }

typedef __attribute__((address_space(1))) const char GChar;
typedef __attribute__((address_space(3))) char LChar;
static __device__ __forceinline__ void gl16(const void* g, void* l) {
    __builtin_amdgcn_global_load_lds((GChar*)g, (LChar*)l, 16, 0, 0);
}
static __device__ __forceinline__ bf16x8v lread(const bf16* base, int row, int slot) {
    const char* p = (const char*)base + (size_t)row * 128 + ((size_t)((slot ^ (row & 7))) << 4);
    return *(const bf16x8v*)p;
}

// ---------------- repack helpers ----------------
static __device__ __forceinline__ void rp1(const float* W, bf16* Wr, int blk, int t,
                                           int N, int K, int Npad, int Kpad) {
    int i = blk * 256 + t;
    if (i >= Npad * Kpad) return;
    int n = i / Kpad, k = i % Kpad;
    float v = (n < N && k < K) ? W[n * K + k] : 0.f;
    Wr[i] = tob(v);
}
static __device__ __forceinline__ void rp3(const float* W, bf16* Wr, int blk, int t,
                                           int N, int K, int Npad, int Kpad) {
    int i = blk * 256 + t;
    int NK = Npad * Kpad;
    if (i >= NK) return;
    int n = i / Kpad, k = i % Kpad;
    if (n < N && k < K) {
        const float* src = W + ((size_t)(n * K + k)) * 9;
#pragma unroll
        for (int q = 0; q < 9; q++) Wr[(size_t)q * NK + i] = tob(src[q]);
    } else {
#pragma unroll
        for (int q = 0; q < 9; q++) Wr[(size_t)q * NK + i] = tob(0.f);
    }
}

// ---------------- fused: all repacks + zero page + both NCHW LayerNorms ---------------
__global__ __launch_bounds__(256) void k_repack_ln(
    const float* __restrict__ qw, const float* __restrict__ kvw,
    const float* __restrict__ projw, const float* __restrict__ pinw,
    const float* __restrict__ poutw, const float* __restrict__ qdww,
    const float* __restrict__ dww,
    bf16* __restrict__ Wq1, bf16* __restrict__ Wkv, bf16* __restrict__ Wproj,
    bf16* __restrict__ Wpin, bf16* __restrict__ Wpout, bf16* __restrict__ Wqdw,
    bf16* __restrict__ Wdw, char* __restrict__ zpage,
    const float* __restrict__ X0, const float* __restrict__ X1,
    const float* __restrict__ w0, const float* __restrict__ b0,
    const float* __restrict__ w1, const float* __restrict__ b1,
    bf16* __restrict__ out0, bf16* __restrict__ out1) {
    __shared__ float lds[64][C_ + 1];
    int blk = blockIdx.x, t = threadIdx.x;
    if (blk < 144)        { rp1(qw,    Wq1,   blk,        t, 192, 192, 192, 192); return; }
    else if (blk < 432)   { rp1(kvw,   Wkv,   blk - 144,  t, 384, 192, 384, 192); return; }
    else if (blk < 576)   { rp1(projw, Wproj, blk - 432,  t, 192, 192, 192, 192); return; }
    else if (blk < 960)   { rp1(pinw,  Wpin,  blk - 576,  t, 510, 192, 512, 192); return; }
    else if (blk < 1344)  { rp1(poutw, Wpout, blk - 960,  t, 192, 510, 192, 512); return; }
    else if (blk < 1488)  { rp3(qdww,  Wqdw,  blk - 1344, t, 192, 192, 192, 192); return; }
    else if (blk < 2512)  { rp3(dww,   Wdw,   blk - 1488, t, 510, 510, 512, 512); return; }
    else if (blk == 2512) { ((uint4*)zpage)[t] = make_uint4(0u, 0u, 0u, 0u); return; }
    int lb = blk - 2513;
    int sel = lb >> 9, xb = lb & 511;
    const float* X = sel ? X1 : X0;
    const float* w = sel ? w1 : w0;
    const float* bb = sel ? b1 : b0;
    bf16* out = sel ? out1 : out0;
    int p0 = xb * 64;
    int b = p0 / HW_, pi0 = p0 % HW_;
    for (int i = t; i < 64 * C_ / 4; i += 256) {
        int c = i >> 4, pp4 = (i & 15) << 2;
        float4 v = *(const float4*)(X + ((size_t)(b * C_ + c)) * HW_ + pi0 + pp4);
        lds[pp4 + 0][c] = v.x; lds[pp4 + 1][c] = v.y;
        lds[pp4 + 2][c] = v.z; lds[pp4 + 3][c] = v.w;
    }
    __syncthreads();
    int pp = t >> 2, qq = t & 3;
    float s = 0.f, s2 = 0.f;
    for (int c = qq * 48; c < qq * 48 + 48; c++) { float v = lds[pp][c]; s += v; s2 += v * v; }
    s  += __shfl_xor(s, 1);  s  += __shfl_xor(s, 2);
    s2 += __shfl_xor(s2, 1); s2 += __shfl_xor(s2, 2);
    float mu = s / C_;
    float rstd = rsqrtf(s2 / C_ - mu * mu + 1e-5f);
    bf16* ob = out + ((size_t)(p0 + pp)) * C_ + qq * 48;
#pragma unroll
    for (int j = 0; j < 6; j++) {
        union { bf16 h[8]; uint4 u; } ov;
#pragma unroll
        for (int e = 0; e < 8; e++) {
            int c = qq * 48 + j * 8 + e;
            ov.h[e] = tob((lds[pp][c] - mu) * rstd * w[c] + bb[c]);
        }
        *(uint4*)(ob + j * 8) = ov.u;
    }
}

// LayerNorm from [p][c] bf16 -> [p][c] bf16 (vectorized)
__global__ __launch_bounds__(256) void k_ln_pc(const bf16* __restrict__ X2,
                                               const float* __restrict__ w,
                                               const float* __restrict__ bb,
                                               bf16* __restrict__ out) {
    int t = threadIdx.x;
    int p = blockIdx.x * 64 + (t >> 2), qq = t & 3;
    const bf16* row = X2 + (size_t)p * C_ + qq * 48;
    uint4 u[6];
#pragma unroll
    for (int j = 0; j < 6; j++) u[j] = *(const uint4*)(row + j * 8);
    float s = 0.f, s2 = 0.f;
#pragma unroll
    for (int j = 0; j < 6; j++) {
        const bf16* pv = (const bf16*)&u[j];
#pragma unroll
        for (int e = 0; e < 8; e++) { float v = fb(pv[e]); s += v; s2 += v * v; }
    }
    s  += __shfl_xor(s, 1);  s  += __shfl_xor(s, 2);
    s2 += __shfl_xor(s2, 1); s2 += __shfl_xor(s2, 2);
    float mu = s / C_;
    float rstd = rsqrtf(s2 / C_ - mu * mu + 1e-5f);
    bf16* orow = out + (size_t)p * C_ + qq * 48;
#pragma unroll
    for (int j = 0; j < 6; j++) {
        const bf16* pv = (const bf16*)&u[j];
        union { bf16 h[8]; uint4 u4; } ov;
#pragma unroll
        for (int e = 0; e < 8; e++) {
            int c = qq * 48 + j * 8 + e;
            ov.h[e] = tob((fb(pv[e]) - mu) * rstd * w[c] + bb[c]);
        }
        *(uint4*)(orow + j * 8) = ov.u4;
    }
}

// ---------------- 1x1 conv GEMM body (global_load_lds + swizzle), BK=64 ---------------
template <int BN, int EPI>
static __device__ __forceinline__ void gemm1x1_body(const bf16* __restrict__ A,
                                                    const bf16* __restrict__ Wbase,
                                                    const int K, const int Cout,
                                                    void* __restrict__ outp,
                                                    const void* __restrict__ resid,
                                                    const int mt, const int n0) {
    constexpr int WN = BN / 2, FN = WN / 16, BIT = BN / 32;
    __shared__ __align__(16) bf16 As[128 * 64];
    __shared__ __align__(16) bf16 Bs[BN * 64];
    const int t = threadIdx.x;
    const int b = mt >> 7, y = mt & 127;
    const int w = t >> 6, lane = t & 63;
    const int wm = w >> 1, wn = w & 1;
    const int g = lane >> 4, r = lane & 15;
    const int ldw = t - lane;

    f32x4 acc[4][FN];
#pragma unroll
    for (int i = 0; i < 4; i++)
#pragma unroll
        for (int j = 0; j < FN; j++) acc[i][j] = {0.f, 0.f, 0.f, 0.f};

    const bf16* Abase = A + (size_t)mt * 128 * K;

    for (int c0 = 0; c0 < K; c0 += 64) {
#pragma unroll
        for (int it = 0; it < 4; it++) {
            int idx = it * 256 + t;
            int row = idx >> 3, sl = idx & 7;
            const char* gp = (const char*)(Abase + (size_t)row * K + c0) + ((sl ^ (row & 7)) << 4);
            gl16(gp, (char*)As + (size_t)(it * 256 + ldw) * 16);
        }
#pragma unroll
        for (int it = 0; it < BIT; it++) {
            int idx = it * 256 + t;
            int row = idx >> 3, sl = idx & 7;
            const char* gp = (const char*)(Wbase + (size_t)(n0 + row) * K + c0) + ((sl ^ (row & 7)) << 4);
            gl16(gp, (char*)Bs + (size_t)(it * 256 + ldw) * 16);
        }
        __syncthreads();
#pragma unroll
        for (int ks = 0; ks < 2; ks++) {
            bf16x8v af[4], bv[FN];
#pragma unroll
            for (int fm = 0; fm < 4; fm++)
                af[fm] = lread(As, wm * 64 + fm * 16 + r, ks * 4 + g);
#pragma unroll
            for (int fn = 0; fn < FN; fn++)
                bv[fn] = lread(Bs, wn * WN + fn * 16 + r, ks * 4 + g);
#pragma unroll
            for (int fm = 0; fm < 4; fm++)
#pragma unroll
                for (int fn = 0; fn < FN; fn++)
                    acc[fm][fn] = __builtin_amdgcn_mfma_f32_16x16x32_bf16(af[fm], bv[fn], acc[fm][fn], 0, 0, 0);
        }
        __syncthreads();
    }

#pragma unroll
    for (int fm = 0; fm < 4; fm++)
#pragma unroll
        for (int fn = 0; fn < FN; fn++)
#pragma unroll
            for (int reg = 0; reg < 4; reg++) {
                int xl = wm * 64 + fm * 16 + g * 4 + reg;
                int co = n0 + wn * WN + fn * 16 + r;
                float v = acc[fm][fn][reg];
                if constexpr (EPI == 1) {
                    ((bf16*)outp)[((size_t)mt * 128 + xl) * Cout + co] = tob(v);
                } else if constexpr (EPI == 2) {
                    v += ((const float*)resid)[((size_t)(b * C_ + co)) * HW_ + y * 128 + xl];
                    ((bf16*)outp)[((size_t)mt * 128 + xl) * C_ + co] = tob(v);
                } else {
                    v += fb(((const bf16*)resid)[((size_t)mt * 128 + xl) * C_ + co]);
                    ((float*)outp)[((size_t)(b * C_ + co)) * HW_ + y * 128 + xl] = v;
                }
            }
}

template <int BN, int EPI>
__global__ __launch_bounds__(256) void k_gemm1x1(const bf16* __restrict__ A,
                                                 const bf16* __restrict__ Wr,
                                                 const int K, const int Cout,
                                                 void* __restrict__ outp,
                                                 const void* __restrict__ resid,
                                                 const int wbstride) {
    const int mt = blockIdx.x;
    const bf16* Wbase = Wr + (size_t)(mt >> 7) * wbstride;
    gemm1x1_body<BN, EPI>(A, Wbase, K, Cout, outp, resid, mt, blockIdx.y * BN);
}

// fused q-1x1 (y 0..1) + kv-1x1 (y 2..5), both BN=96, K=192
__global__ __launch_bounds__(256) void k_qkv(const bf16* __restrict__ iln,
                                             const bf16* __restrict__ xn,
                                             const bf16* __restrict__ Wq1,
                                             const bf16* __restrict__ Wkv,
                                             bf16* __restrict__ qtmp,
                                             bf16* __restrict__ kvtmp) {
    const bool isq = blockIdx.y < 2;
    const bf16* A = isq ? iln : xn;
    const bf16* Wr = isq ? Wq1 : Wkv;
    bf16* outp = isq ? qtmp : kvtmp;
    const int Cout = isq ? 192 : 384;
    const int n0 = (isq ? blockIdx.y : blockIdx.y - 2) * 96;
    gemm1x1_body<96, 1>(A, Wr, 192, Cout, outp, nullptr, blockIdx.x, n0);
}

// ---------------- 3x3 full conv implicit GEMM, simple 2-barrier + XCD mt-swizzle ------
// (used for qdw 192->192)
template <int BN, int EPI>
__global__ __launch_bounds__(256) void k_gemm3x3(const bf16* __restrict__ A,
                                                 const bf16* __restrict__ Wr,
                                                 const int Cin, const int Cout,
                                                 bf16* __restrict__ outp,
                                                 const char* __restrict__ zpage) {
    constexpr int WN = BN / 2, FN = WN / 16, BIT = BN / 32;
    __shared__ __align__(16) bf16 As[160 * 64];
    __shared__ __align__(16) bf16 Bs[BN * 64];
    const int t = threadIdx.x;
    const int mtRaw = blockIdx.x;
    const int mt = ((mtRaw & 7) << 5) | (mtRaw >> 3);
    const int n0 = blockIdx.y * BN;
    const int b = mt >> 7, y = mt & 127;
    const int w = t >> 6, lane = t & 63;
    const int wm = w >> 1, wn = w & 1;
    const int g = lane >> 4, r = lane & 15;
    const int ldw = t - lane;

    f32x4 acc[4][FN];
#pragma unroll
    for (int i = 0; i < 4; i++)
#pragma unroll
        for (int j = 0; j < FN; j++) acc[i][j] = {0.f, 0.f, 0.f, 0.f};

    for (int ky = 0; ky < 3; ky++) {
        const int yy = y + ky - 1;
        if (yy < 0 || yy > 127) continue;   // block-uniform
        const bf16* Ab = A + ((size_t)b * HW_ + (size_t)yy * 128) * Cin;
        for (int c0 = 0; c0 < Cin; c0 += 64) {
            for (int kx = 0; kx < 3; kx++) {
                if (kx == 0) {
#pragma unroll
                    for (int it = 0; it < 5; it++) {
                        int idx = it * 256 + t;
                        int row = idx >> 3, sl = idx & 7;
                        int so = (sl ^ (row & 7)) << 4;
                        const char* gp = (row >= 1 && row <= 128)
                            ? (const char*)(Ab + (size_t)(row - 1) * Cin + c0) + so
                            : zpage + so;
                        gl16(gp, (char*)As + (size_t)(it * 256 + ldw) * 16);
                    }
                }
                const bf16* Wb = Wr + (size_t)(ky * 3 + kx) * Cout * Cin;
#pragma unroll
                for (int it = 0; it < BIT; it++) {
                    int idx = it * 256 + t;
                    int row = idx >> 3, sl = idx & 7;
                    const char* gp = (const char*)(Wb + (size_t)(n0 + row) * Cin + c0) + ((sl ^ (row & 7)) << 4);
                    gl16(gp, (char*)Bs + (size_t)(it * 256 + ldw) * 16);
                }
                __syncthreads();
#pragma unroll
                for (int ks = 0; ks < 2; ks++) {
                    bf16x8v af[4], bv[FN];
#pragma unroll
                    for (int fm = 0; fm < 4; fm++)
                        af[fm] = lread(As, wm * 64 + fm * 16 + r + kx, ks * 4 + g);
#pragma unroll
                    for (int fn = 0; fn < FN; fn++)
                        bv[fn] = lread(Bs, wn * WN + fn * 16 + r, ks * 4 + g);
#pragma unroll
                    for (int fm = 0; fm < 4; fm++)
#pragma unroll
                        for (int fn = 0; fn < FN; fn++)
                            acc[fm][fn] = __builtin_amdgcn_mfma_f32_16x16x32_bf16(af[fm], bv[fn], acc[fm][fn], 0, 0, 0);
                }
                __syncthreads();
            }
        }
    }
#pragma unroll
    for (int fm = 0; fm < 4; fm++)
#pragma unroll
        for (int fn = 0; fn < FN; fn++)
#pragma unroll
            for (int reg = 0; reg < 4; reg++) {
                int xl = wm * 64 + fm * 16 + g * 4 + reg;
                int co = n0 + wn * WN + fn * 16 + r;
                float v = acc[fm][fn][reg];
                if constexpr (EPI == 1) v = 0.5f * v * (1.0f + erff(v * 0.70710678118654752f));
                outp[((size_t)mt * 128 + xl) * Cout + co] = tob(v);
            }
}

// ---------------- dw 3x3 512->512, BM=256 (2 image rows), 512 thr, 2-barrier ----------
// A tile: 2 x 160 rows x 64ch (40KB, single-buf); B: 128 x 64 (16KB). GELU epilogue.
__global__ __launch_bounds__(512) void k_dw3x3b(const bf16* __restrict__ A,
                                                const bf16* __restrict__ Wr,
                                                bf16* __restrict__ outp,
                                                const char* __restrict__ zpage) {
    constexpr int CI = 512, CO = 512;
    __shared__ __align__(16) bf16 As[320 * 64];   // [rr*160 + 1+x][c]
    __shared__ __align__(16) bf16 Bs[128 * 64];
    const int t = threadIdx.x;
    const int mtRaw = blockIdx.x;                 // 128
    const int mt = ((mtRaw & 7) << 4) | (mtRaw >> 3);   // XCD-contiguous
    const int n0 = blockIdx.y * 128;
    const int b = mt >> 6, y0 = mt & 63;          // image rows 2y0, 2y0+1
    const int w = t >> 6, lane = t & 63;
    const int wm = w >> 1, wn = w & 1;            // 4M x 2N waves
    const int g = lane >> 4, r = lane & 15;

    f32x4 acc[4][4];
#pragma unroll
    for (int i = 0; i < 4; i++)
#pragma unroll
        for (int j = 0; j < 4; j++) acc[i][j] = {0.f, 0.f, 0.f, 0.f};

    for (int ky = 0; ky < 3; ky++) {
        for (int c0 = 0; c0 < CI; c0 += 64) {
            for (int kx = 0; kx < 3; kx++) {
                if (kx == 0) {
                    // stage A: 320 rows x 64ch, per-lane zpage redirect for borders
#pragma unroll
                    for (int it = 0; it < 5; it++) {
                        int idx = it * 512 + t;
                        int row = idx >> 3, sl = idx & 7;
                        int so = (sl ^ (row & 7)) << 4;
                        int rr = (row >= 160) ? 1 : 0;
                        int xr = row - rr * 160;
                        int ya = 2 * y0 + ky - 1 + rr;
                        bool valid = (xr >= 1 && xr <= 128 && ya >= 0 && ya <= 127);
                        const char* gp = valid
                            ? (const char*)(A + ((size_t)(b * HW_ + ya * 128 + xr - 1)) * CI + c0) + so
                            : zpage + so;
                        gl16(gp, (char*)As + (size_t)(it * 512 + (t - lane)) * 16);
                    }
                }
                const bf16* Wb = Wr + (size_t)(ky * 3 + kx) * CO * CI + c0;
#pragma unroll
                for (int it = 0; it < 2; it++) {
                    int idx = it * 512 + t;
                    int row = idx >> 3, sl = idx & 7;
                    const char* gp = (const char*)(Wb + (size_t)(n0 + row) * CI) + ((sl ^ (row & 7)) << 4);
                    gl16(gp, (char*)Bs + (size_t)(it * 512 + (t - lane)) * 16);
                }
                __syncthreads();
#pragma unroll
                for (int ks = 0; ks < 2; ks++) {
                    bf16x8v af[4], bv[4];
#pragma unroll
                    for (int fm = 0; fm < 4; fm++) {
                        int p = wm * 64 + fm * 16 + r;
                        int rowA = ((p >> 7) * 160) + (p & 127) + kx;
                        af[fm] = lread(As, rowA, ks * 4 + g);
                    }
#pragma unroll
                    for (int fn = 0; fn < 4; fn++)
                        bv[fn] = lread(Bs, wn * 64 + fn * 16 + r, ks * 4 + g);
#pragma unroll
                    for (int fm = 0; fm < 4; fm++)
#pragma unroll
                        for (int fn = 0; fn < 4; fn++)
                            acc[fm][fn] = __builtin_amdgcn_mfma_f32_16x16x32_bf16(af[fm], bv[fn], acc[fm][fn], 0, 0, 0);
                }
                __syncthreads();
            }
        }
    }
#pragma unroll
    for (int fm = 0; fm < 4; fm++)
#pragma unroll
        for (int fn = 0; fn < 4; fn++)
#pragma unroll
            for (int reg = 0; reg < 4; reg++) {
                int p = wm * 64 + fm * 16 + g * 4 + reg;
                int yloc = p >> 7, xx = p & 127;
                int co = n0 + wn * 64 + fn * 16 + r;
                float v = acc[fm][fn][reg];
                v = 0.5f * v * (1.0f + erff(v * 0.70710678118654752f));
                outp[((size_t)(b * HW_ + (2 * y0 + yloc) * 128 + xx)) * CO + co] = tob(v);
            }
}

// ---------------- depthwise 3x3: sliding-window cols, 16 contiguous x per thread -------
__global__ __launch_bounds__(192) void k_dwconv2(const bf16* __restrict__ kv,
                                                 const float* __restrict__ wdw,
                                                 bf16* __restrict__ kout,
                                                 bf16* __restrict__ vout) {
    __shared__ float wlds[1728];
    const int t = threadIdx.x;
    const int row = blockIdx.x;
    const int z = blockIdx.y;
    const int b = row >> 7, y = row & 127;
    for (int i = t; i < 432; i += 192)
        ((float4*)wlds)[i] = ((const float4*)(wdw + (size_t)z * 1728))[i];
    __syncthreads();
    const int c8h = t % 24, xg = t / 24;
    const int cbase = z * C_ + c8h * 8;
    float wreg[9][8];
#pragma unroll
    for (int tap = 0; tap < 9; tap++)
#pragma unroll
        for (int j = 0; j < 8; j++) wreg[tap][j] = wlds[(c8h * 8 + j) * 9 + tap];

    bf16* outb = (z == 0 ? kout : vout) + (size_t)(b * HW_ + y * 128) * C_ + c8h * 8;
    const uint4 zero4 = make_uint4(0u, 0u, 0u, 0u);
    const int x0 = xg * 16;
    bool vy[3]; const bf16* rowp[3];
#pragma unroll
    for (int ky = 0; ky < 3; ky++) {
        int yy = y + ky - 1;
        vy[ky] = (yy >= 0 && yy <= 127);
        int yyc = vy[ky] ? yy : 0;
        rowp[ky] = kv + ((size_t)b * HW_ + (size_t)yyc * 128) * C2_ + cbase;
    }
    uint4 win[3][3];
#pragma unroll
    for (int ky = 0; ky < 3; ky++) {
        win[ky][0] = (vy[ky] && x0 - 1 >= 0) ? *(const uint4*)(rowp[ky] + (size_t)(x0 - 1) * C2_) : zero4;
        win[ky][1] = vy[ky] ? *(const uint4*)(rowp[ky] + (size_t)x0 * C2_) : zero4;
    }
    for (int i = 0; i < 16; i++) {
        int x = x0 + i;
#pragma unroll
        for (int ky = 0; ky < 3; ky++)
            win[ky][2] = (vy[ky] && x + 1 <= 127) ? *(const uint4*)(rowp[ky] + (size_t)(x + 1) * C2_) : zero4;
        float acc[8];
#pragma unroll
        for (int j = 0; j < 8; j++) acc[j] = 0.f;
#pragma unroll
        for (int ky = 0; ky < 3; ky++)
#pragma unroll
            for (int kx = 0; kx < 3; kx++) {
                const bf16* pv = (const bf16*)&win[ky][kx];
#pragma unroll
                for (int j = 0; j < 8; j++)
                    acc[j] += fb(pv[j]) * wreg[ky * 3 + kx][j];
            }
        union { bf16 h[8]; uint4 u; } ov;
#pragma unroll
        for (int j = 0; j < 8; j++) ov.h[j] = tob(acc[j]);
        *(uint4*)(outb + (size_t)x * C_) = ov.u;
#pragma unroll
        for (int ky = 0; ky < 3; ky++) { win[ky][0] = win[ky][1]; win[ky][1] = win[ky][2]; }
    }
}

// ---------------- S partials + fused ssq: per (b,hd,chunk) over 256 positions ----------
__global__ __launch_bounds__(256) void k_qk(const bf16* __restrict__ q,
                                            const bf16* __restrict__ k,
                                            float* __restrict__ Spart,
                                            float* __restrict__ ssq) {
    __shared__ float qs[64][49];
    __shared__ float ks[64][49];
    __shared__ float redq[4][48], redk[4][48];
    int t = threadIdx.x;
    int ch = blockIdx.x, hd = blockIdx.y, b = blockIdx.z;
    int i0 = (t >> 4) * 3, j0 = (t & 15) * 3;
    int cs = t % 48, qr = t / 48;
    float acc[3][3];
    float sq = 0.f, sk = 0.f;
#pragma unroll
    for (int a = 0; a < 3; a++)
#pragma unroll
        for (int c = 0; c < 3; c++) acc[a][c] = 0.f;

    for (int sub = 0; sub < 4; sub++) {
        size_t rbase = ((size_t)b * HW_ + ch * 256 + sub * 64) * C_ + hd * 48;
        for (int i = t; i < 64 * 6; i += 256) {
            int row = i / 6, oc = i % 6;
            uint4 v = *(const uint4*)(q + rbase + (size_t)row * C_ + oc * 8);
            const bf16* pv = (const bf16*)&v;
#pragma unroll
            for (int j = 0; j < 8; j++) qs[row][oc * 8 + j] = fb(pv[j]);
            uint4 v2 = *(const uint4*)(k + rbase + (size_t)row * C_ + oc * 8);
            const bf16* pv2 = (const bf16*)&v2;
#pragma unroll
            for (int j = 0; j < 8; j++) ks[row][oc * 8 + j] = fb(pv2[j]);
        }
        __syncthreads();
        if (t < 192) {
#pragma unroll
            for (int rr = 0; rr < 16; rr++) {
                float qv = qs[qr * 16 + rr][cs]; sq += qv * qv;
                float kv2 = ks[qr * 16 + rr][cs]; sk += kv2 * kv2;
            }
        }
        for (int p = 0; p < 64; p++) {
            float a0 = qs[p][i0], a1 = qs[p][i0 + 1], a2 = qs[p][i0 + 2];
            float b0 = ks[p][j0], b1 = ks[p][j0 + 1], b2 = ks[p][j0 + 2];
            acc[0][0] += a0 * b0; acc[0][1] += a0 * b1; acc[0][2] += a0 * b2;
            acc[1][0] += a1 * b0; acc[1][1] += a1 * b1; acc[1][2] += a1 * b2;
            acc[2][0] += a2 * b0; acc[2][1] += a2 * b1; acc[2][2] += a2 * b2;
        }
        __syncthreads();
    }
    if (t < 192) { redq[qr][cs] = sq; redk[qr][cs] = sk; }
    float* dst = Spart + (((size_t)(b * 4 + hd)) * 64 + ch) * 2304;
#pragma unroll
    for (int a = 0; a < 3; a++)
#pragma unroll
        for (int c = 0; c < 3; c++) dst[(i0 + a) * 48 + (j0 + c)] = acc[a][c];
    __syncthreads();
    if (t < 48) {
        float s0 = redq[0][t] + redq[1][t] + redq[2][t] + redq[3][t];
        float s1 = redk[0][t] + redk[1][t] + redk[2][t] + redk[3][t];
        ssq[((size_t)b * 64 + ch) * C_ + hd * 48 + t] = s0;
        ssq[((size_t)(2 + b) * 64 + ch) * C_ + hd * 48 + t] = s1;
    }
}

// ---------------- softmax: reduce 64 chunks, fused inv-norms, emit diag-block bf16 ----
__global__ __launch_bounds__(256) void k_softmax(const float* __restrict__ Spart,
                                                 const float* __restrict__ ssq,
                                                 const float* __restrict__ temp,
                                                 bf16* __restrict__ attnW) {
    __shared__ float S[2304];
    __shared__ float invk_s[48];
    int t = threadIdx.x;
    int hd = blockIdx.x, b = blockIdx.y;
    const float* base = Spart + ((size_t)(b * 4 + hd)) * 64 * 2304;
    for (int e = t; e < 2304; e += 256) {
        float s = 0.f;
        for (int ch = 0; ch < 64; ch++) s += base[(size_t)ch * 2304 + e];
        S[e] = s;
    }
    if (t < 48) {
        int c = hd * 48 + t;
        float sk = 0.f;
        for (int ch = 0; ch < 64; ch++) sk += ssq[((size_t)(2 + b) * 64 + ch) * C_ + c];
        invk_s[t] = 1.f / fmaxf(sqrtf(sk), 1e-12f);
    }
    __syncthreads();
    if (t >= 48) return;
    int c = hd * 48 + t;
    float sq = 0.f;
    for (int ch = 0; ch < 64; ch++) sq += ssq[((size_t)b * 64 + ch) * C_ + c];
    float qi = 1.f / fmaxf(sqrtf(sq), 1e-12f);
    float tp = temp[hd];
    float row[48];
    float mx = -1e30f;
    for (int j = 0; j < 48; j++) {
        float s = S[t * 48 + j] * qi * invk_s[j] * tp;
        row[j] = s;
        mx = fmaxf(mx, s);
    }
    float sum = 0.f;
    for (int j = 0; j < 48; j++) { row[j] = expf(row[j] - mx); sum += row[j]; }
    float is = 1.f / sum;
    bf16* wrow = attnW + ((size_t)b * 192 + hd * 48 + t) * 192 + hd * 48;
    for (int j = 0; j < 48; j++) wrow[j] = tob(row[j] * is);
}

// ---------------- M[b][c2][c0] = sum_{c1 in head(c0)} Wproj[c2][c1]*attn[b][c1][c0] ----
__global__ __launch_bounds__(256) void k_wav(const bf16* __restrict__ Wproj,
                                             const bf16* __restrict__ attnW,
                                             bf16* __restrict__ Mw) {
    int bid = blockIdx.x;
    int b = bid / 12, rg = bid % 12;
    int t = threadIdx.x;
    int row = rg * 16 + (t >> 4);
    int c0b = (t & 15) * 12;
    int hd = c0b / 48;
    const bf16* aw = attnW + (size_t)b * 36864;
    float acc[12];
#pragma unroll
    for (int j = 0; j < 12; j++) acc[j] = 0.f;
    for (int k = hd * 48; k < hd * 48 + 48; k++) {
        float wp = fb(Wproj[row * 192 + k]);
        const bf16* ar = aw + (size_t)k * 192 + c0b;
#pragma unroll
        for (int j = 0; j < 12; j++) acc[j] += wp * fb(ar[j]);
    }
    bf16* mrow = Mw + ((size_t)b * 192 + row) * 192 + c0b;
#pragma unroll
    for (int j = 0; j < 12; j++) mrow[j] = tob(acc[j]);
}

// =====================================================================================
extern "C" void kernel_launch(void* const* d_in, const int* in_sizes, int n_in,
                              void* d_out, int out_size, void* d_ws, size_t ws_size,
                              hipStream_t stream) {
    const float* x     = (const float*)d_in[0];
    const float* illum = (const float*)d_in[1];
    const float* ln1w  = (const float*)d_in[2];
    const float* ln1b  = (const float*)d_in[3];
    const float* lnLw  = (const float*)d_in[4];
    const float* lnLb  = (const float*)d_in[5];
    const float* ln2w  = (const float*)d_in[6];
    const float* ln2b  = (const float*)d_in[7];
    const float* qw    = (const float*)d_in[8];
    const float* qdww  = (const float*)d_in[9];
    const float* kvw   = (const float*)d_in[10];
    const float* kvdww = (const float*)d_in[11];
    const float* temp  = (const float*)d_in[12];
    const float* projw = (const float*)d_in[13];
    const float* pinw  = (const float*)d_in[14];
    const float* dww   = (const float*)d_in[15];
    const float* poutw = (const float*)d_in[16];

    char* ws = (char*)d_ws;
    bf16*  Wq1   = (bf16*)(ws + 0);
    bf16*  Wkv   = (bf16*)(ws + 73728);
    bf16*  Wqdw  = (bf16*)(ws + 221184);
    bf16*  Wproj = (bf16*)(ws + 884736);
    bf16*  Wpin  = (bf16*)(ws + 958464);
    bf16*  Wdw   = (bf16*)(ws + 1155072);
    bf16*  Wpout = (bf16*)(ws + 5873664);
    float* ssq   = (float*)(ws + 6070272);
    char*  zpage = (char*)(ws + 6266880);
    const size_t A0 = 6270976, u = 12582912;
    bf16* xn    = (bf16*)(ws + A0 + 0 * u);      // [LN1, qkv]
    bf16* iln   = (bf16*)(ws + A0 + 1 * u);      // [LNL, qkv]
    bf16* kvtmp = (bf16*)(ws + A0 + 2 * u);      // [qkv, dwconv] slots 2-3
    bf16* qtmp  = (bf16*)(ws + A0 + 4 * u);      // [qkv, q-3x3] slot4-lo
    bf16* qb    = (bf16*)(ws + A0 + 1 * u);      // [q-3x3, qk]
    bf16* kb    = (bf16*)(ws + A0 + 0 * u);      // wait: xn lives until qkv done; kb written by dwconv (after qkv) -> safe
    bf16* vb    = (bf16*)(ws + A0 + 4 * u + 12582912); // [dwconv, proj-gemm] slot4-hi
    float* Spart = (float*)(ws + A0 + 3 * u);          // [qk, softmax]
    bf16*  attnW = (bf16*)(ws + A0 + 3 * u + 4718592);
    bf16*  Mw    = (bf16*)(ws + A0 + 3 * u + 4866048);
    bf16* x2    = (bf16*)(ws + A0 + 0 * u);      // [proj, pout]
    bf16* xn2   = (bf16*)(ws + A0 + 3 * u);      // [LN2, pin]
    bf16* fbuf  = (bf16*)(ws + A0 + 4 * u);      // [pin, dw3x3] 33.5 MB
    bf16* gbuf  = (bf16*)(ws + A0 + 1 * u);      // [dw3x3, pout] 33.5 MB

    // 0) repacks + zpage + both NCHW LayerNorms, one launch
    k_repack_ln<<<3537, 256, 0, stream>>>(qw, kvw, projw, pinw, poutw, qdww, dww,
                                          Wq1, Wkv, Wproj, Wpin, Wpout, Wqdw, Wdw, zpage,
                                          x, illum, ln1w, ln1b, lnLw, lnLb, xn, iln);

    // 1) q-1x1 + kv-1x1 fused
    k_qkv<<<dim3(256, 6), 256, 0, stream>>>(iln, xn, Wq1, Wkv, qtmp, kvtmp);

    // 2) q full 3x3 -> qb ; kv depthwise -> kb, vb
    k_gemm3x3<96, 0><<<dim3(256, 2), 256, 0, stream>>>(qtmp, Wqdw, 192, 192, qb, zpage);
    k_dwconv2<<<dim3(256, 2), 192, 0, stream>>>(kvtmp, kvdww, kb, vb);

    // 3) attention
    k_qk<<<dim3(64, 4, 2), 256, 0, stream>>>(qb, kb, Spart, ssq);
    k_softmax<<<dim3(4, 2), 256, 0, stream>>>(Spart, ssq, temp, attnW);
    k_wav<<<24, 256, 0, stream>>>(Wproj, attnW, Mw);

    // 4) x2 = x + v @ (proj∘attn)
    k_gemm1x1<96, 2><<<dim3(256, 2), 256, 0, stream>>>(vb, Mw, 192, 192, x2, x, 36864);

    // 5) FFN
    k_ln_pc<<<512, 256, 0, stream>>>(x2, ln2w, ln2b, xn2);
    k_gemm1x1<128, 1><<<dim3(256, 4), 256, 0, stream>>>(xn2, Wpin, 192, 512, fbuf, nullptr, 0);
    k_dw3x3b<<<dim3(128, 4), 512, 0, stream>>>(fbuf, Wdw, gbuf, zpage);
    k_gemm1x1<96, 3><<<dim3(256, 2), 256, 0, stream>>>(gbuf, Wpout, 512, 192, d_out, x2, 0);
}

// Round 12
// 369.570 us; speedup vs baseline: 1.0542x; 1.0542x over previous
//
#include <hip/hip_runtime.h>
#include <hip/hip_bf16.h>

typedef __hip_bfloat16 bf16;
typedef __attribute__((ext_vector_type(8))) short bf16x8v;
typedef __attribute__((ext_vector_type(4))) float f32x4;

namespace {
constexpr int B_  = 2;
constexpr int C_  = 192;
constexpr int HW_ = 128 * 128;   // 16384
constexpr int C2_ = 384;
}

static __device__ __forceinline__ float fb(bf16 v) { return __bfloat162float(v); }
static __device__ __forceinline__ bf16 tob(float v) { return __float2bfloat16(v); }

typedef __attribute__((address_space(1))) const char GChar;
typedef __attribute__((address_space(3))) char LChar;
static __device__ __forceinline__ void gl16(const void* g, void* l) {
    __builtin_amdgcn_global_load_lds((GChar*)g, (LChar*)l, 16, 0, 0);
}
static __device__ __forceinline__ bf16x8v lread(const bf16* base, int row, int slot) {
    const char* p = (const char*)base + (size_t)row * 128 + ((size_t)((slot ^ (row & 7))) << 4);
    return *(const bf16x8v*)p;
}

// ---------------- repack helpers ----------------
static __device__ __forceinline__ void rp1(const float* W, bf16* Wr, int blk, int t,
                                           int N, int K, int Npad, int Kpad) {
    int i = blk * 256 + t;
    if (i >= Npad * Kpad) return;
    int n = i / Kpad, k = i % Kpad;
    float v = (n < N && k < K) ? W[n * K + k] : 0.f;
    Wr[i] = tob(v);
}
static __device__ __forceinline__ void rp3(const float* W, bf16* Wr, int blk, int t,
                                           int N, int K, int Npad, int Kpad) {
    int i = blk * 256 + t;
    int NK = Npad * Kpad;
    if (i >= NK) return;
    int n = i / Kpad, k = i % Kpad;
    if (n < N && k < K) {
        const float* src = W + ((size_t)(n * K + k)) * 9;
#pragma unroll
        for (int q = 0; q < 9; q++) Wr[(size_t)q * NK + i] = tob(src[q]);
    } else {
#pragma unroll
        for (int q = 0; q < 9; q++) Wr[(size_t)q * NK + i] = tob(0.f);
    }
}

// ---------------- fused: all repacks + zero page + both NCHW LayerNorms ---------------
__global__ __launch_bounds__(256) void k_repack_ln(
    const float* __restrict__ qw, const float* __restrict__ kvw,
    const float* __restrict__ projw, const float* __restrict__ pinw,
    const float* __restrict__ poutw, const float* __restrict__ qdww,
    const float* __restrict__ dww,
    bf16* __restrict__ Wq1, bf16* __restrict__ Wkv, bf16* __restrict__ Wproj,
    bf16* __restrict__ Wpin, bf16* __restrict__ Wpout, bf16* __restrict__ Wqdw,
    bf16* __restrict__ Wdw, char* __restrict__ zpage,
    const float* __restrict__ X0, const float* __restrict__ X1,
    const float* __restrict__ w0, const float* __restrict__ b0,
    const float* __restrict__ w1, const float* __restrict__ b1,
    bf16* __restrict__ out0, bf16* __restrict__ out1) {
    __shared__ float lds[64][C_ + 1];
    int blk = blockIdx.x, t = threadIdx.x;
    if (blk < 144)        { rp1(qw,    Wq1,   blk,        t, 192, 192, 192, 192); return; }
    else if (blk < 432)   { rp1(kvw,   Wkv,   blk - 144,  t, 384, 192, 384, 192); return; }
    else if (blk < 576)   { rp1(projw, Wproj, blk - 432,  t, 192, 192, 192, 192); return; }
    else if (blk < 960)   { rp1(pinw,  Wpin,  blk - 576,  t, 510, 192, 512, 192); return; }
    else if (blk < 1344)  { rp1(poutw, Wpout, blk - 960,  t, 192, 510, 192, 512); return; }
    else if (blk < 1488)  { rp3(qdww,  Wqdw,  blk - 1344, t, 192, 192, 192, 192); return; }
    else if (blk < 2512)  { rp3(dww,   Wdw,   blk - 1488, t, 510, 510, 512, 512); return; }
    else if (blk == 2512) { ((uint4*)zpage)[t] = make_uint4(0u, 0u, 0u, 0u); return; }
    int lb = blk - 2513;
    int sel = lb >> 9, xb = lb & 511;
    const float* X = sel ? X1 : X0;
    const float* w = sel ? w1 : w0;
    const float* bb = sel ? b1 : b0;
    bf16* out = sel ? out1 : out0;
    int p0 = xb * 64;
    int b = p0 / HW_, pi0 = p0 % HW_;
    for (int i = t; i < 64 * C_ / 4; i += 256) {
        int c = i >> 4, pp4 = (i & 15) << 2;
        float4 v = *(const float4*)(X + ((size_t)(b * C_ + c)) * HW_ + pi0 + pp4);
        lds[pp4 + 0][c] = v.x; lds[pp4 + 1][c] = v.y;
        lds[pp4 + 2][c] = v.z; lds[pp4 + 3][c] = v.w;
    }
    __syncthreads();
    int pp = t >> 2, qq = t & 3;
    float s = 0.f, s2 = 0.f;
    for (int c = qq * 48; c < qq * 48 + 48; c++) { float v = lds[pp][c]; s += v; s2 += v * v; }
    s  += __shfl_xor(s, 1);  s  += __shfl_xor(s, 2);
    s2 += __shfl_xor(s2, 1); s2 += __shfl_xor(s2, 2);
    float mu = s / C_;
    float rstd = rsqrtf(s2 / C_ - mu * mu + 1e-5f);
    bf16* ob = out + ((size_t)(p0 + pp)) * C_ + qq * 48;
#pragma unroll
    for (int j = 0; j < 6; j++) {
        union { bf16 h[8]; uint4 u; } ov;
#pragma unroll
        for (int e = 0; e < 8; e++) {
            int c = qq * 48 + j * 8 + e;
            ov.h[e] = tob((lds[pp][c] - mu) * rstd * w[c] + bb[c]);
        }
        *(uint4*)(ob + j * 8) = ov.u;
    }
}

// LayerNorm from [p][c] bf16 -> [p][c] bf16 (vectorized)
__global__ __launch_bounds__(256) void k_ln_pc(const bf16* __restrict__ X2,
                                               const float* __restrict__ w,
                                               const float* __restrict__ bb,
                                               bf16* __restrict__ out) {
    int t = threadIdx.x;
    int p = blockIdx.x * 64 + (t >> 2), qq = t & 3;
    const bf16* row = X2 + (size_t)p * C_ + qq * 48;
    uint4 u[6];
#pragma unroll
    for (int j = 0; j < 6; j++) u[j] = *(const uint4*)(row + j * 8);
    float s = 0.f, s2 = 0.f;
#pragma unroll
    for (int j = 0; j < 6; j++) {
        const bf16* pv = (const bf16*)&u[j];
#pragma unroll
        for (int e = 0; e < 8; e++) { float v = fb(pv[e]); s += v; s2 += v * v; }
    }
    s  += __shfl_xor(s, 1);  s  += __shfl_xor(s, 2);
    s2 += __shfl_xor(s2, 1); s2 += __shfl_xor(s2, 2);
    float mu = s / C_;
    float rstd = rsqrtf(s2 / C_ - mu * mu + 1e-5f);
    bf16* orow = out + (size_t)p * C_ + qq * 48;
#pragma unroll
    for (int j = 0; j < 6; j++) {
        const bf16* pv = (const bf16*)&u[j];
        union { bf16 h[8]; uint4 u4; } ov;
#pragma unroll
        for (int e = 0; e < 8; e++) {
            int c = qq * 48 + j * 8 + e;
            ov.h[e] = tob((fb(pv[e]) - mu) * rstd * w[c] + bb[c]);
        }
        *(uint4*)(orow + j * 8) = ov.u4;
    }
}

// ---------------- 1x1 conv GEMM body (global_load_lds + swizzle), BK=64 ---------------
template <int BN, int EPI>
static __device__ __forceinline__ void gemm1x1_body(const bf16* __restrict__ A,
                                                    const bf16* __restrict__ Wbase,
                                                    const int K, const int Cout,
                                                    void* __restrict__ outp,
                                                    const void* __restrict__ resid,
                                                    const int mt, const int n0) {
    constexpr int WN = BN / 2, FN = WN / 16, BIT = BN / 32;
    __shared__ __align__(16) bf16 As[128 * 64];
    __shared__ __align__(16) bf16 Bs[BN * 64];
    const int t = threadIdx.x;
    const int b = mt >> 7, y = mt & 127;
    const int w = t >> 6, lane = t & 63;
    const int wm = w >> 1, wn = w & 1;
    const int g = lane >> 4, r = lane & 15;
    const int ldw = t - lane;

    f32x4 acc[4][FN];
#pragma unroll
    for (int i = 0; i < 4; i++)
#pragma unroll
        for (int j = 0; j < FN; j++) acc[i][j] = {0.f, 0.f, 0.f, 0.f};

    const bf16* Abase = A + (size_t)mt * 128 * K;

    for (int c0 = 0; c0 < K; c0 += 64) {
#pragma unroll
        for (int it = 0; it < 4; it++) {
            int idx = it * 256 + t;
            int row = idx >> 3, sl = idx & 7;
            const char* gp = (const char*)(Abase + (size_t)row * K + c0) + ((sl ^ (row & 7)) << 4);
            gl16(gp, (char*)As + (size_t)(it * 256 + ldw) * 16);
        }
#pragma unroll
        for (int it = 0; it < BIT; it++) {
            int idx = it * 256 + t;
            int row = idx >> 3, sl = idx & 7;
            const char* gp = (const char*)(Wbase + (size_t)(n0 + row) * K + c0) + ((sl ^ (row & 7)) << 4);
            gl16(gp, (char*)Bs + (size_t)(it * 256 + ldw) * 16);
        }
        __syncthreads();
#pragma unroll
        for (int ks = 0; ks < 2; ks++) {
            bf16x8v af[4], bv[FN];
#pragma unroll
            for (int fm = 0; fm < 4; fm++)
                af[fm] = lread(As, wm * 64 + fm * 16 + r, ks * 4 + g);
#pragma unroll
            for (int fn = 0; fn < FN; fn++)
                bv[fn] = lread(Bs, wn * WN + fn * 16 + r, ks * 4 + g);
#pragma unroll
            for (int fm = 0; fm < 4; fm++)
#pragma unroll
                for (int fn = 0; fn < FN; fn++)
                    acc[fm][fn] = __builtin_amdgcn_mfma_f32_16x16x32_bf16(af[fm], bv[fn], acc[fm][fn], 0, 0, 0);
        }
        __syncthreads();
    }

#pragma unroll
    for (int fm = 0; fm < 4; fm++)
#pragma unroll
        for (int fn = 0; fn < FN; fn++)
#pragma unroll
            for (int reg = 0; reg < 4; reg++) {
                int xl = wm * 64 + fm * 16 + g * 4 + reg;
                int co = n0 + wn * WN + fn * 16 + r;
                float v = acc[fm][fn][reg];
                if constexpr (EPI == 1) {
                    ((bf16*)outp)[((size_t)mt * 128 + xl) * Cout + co] = tob(v);
                } else if constexpr (EPI == 2) {
                    v += ((const float*)resid)[((size_t)(b * C_ + co)) * HW_ + y * 128 + xl];
                    ((bf16*)outp)[((size_t)mt * 128 + xl) * C_ + co] = tob(v);
                } else {
                    v += fb(((const bf16*)resid)[((size_t)mt * 128 + xl) * C_ + co]);
                    ((float*)outp)[((size_t)(b * C_ + co)) * HW_ + y * 128 + xl] = v;
                }
            }
}

template <int BN, int EPI>
__global__ __launch_bounds__(256) void k_gemm1x1(const bf16* __restrict__ A,
                                                 const bf16* __restrict__ Wr,
                                                 const int K, const int Cout,
                                                 void* __restrict__ outp,
                                                 const void* __restrict__ resid,
                                                 const int wbstride) {
    const int mt = blockIdx.x;
    const bf16* Wbase = Wr + (size_t)(mt >> 7) * wbstride;
    gemm1x1_body<BN, EPI>(A, Wbase, K, Cout, outp, resid, mt, blockIdx.y * BN);
}

// fused q-1x1 (y 0..1) + kv-1x1 (y 2..5), both BN=96, K=192
__global__ __launch_bounds__(256) void k_qkv(const bf16* __restrict__ iln,
                                             const bf16* __restrict__ xn,
                                             const bf16* __restrict__ Wq1,
                                             const bf16* __restrict__ Wkv,
                                             bf16* __restrict__ qtmp,
                                             bf16* __restrict__ kvtmp) {
    const bool isq = blockIdx.y < 2;
    const bf16* A = isq ? iln : xn;
    const bf16* Wr = isq ? Wq1 : Wkv;
    bf16* outp = isq ? qtmp : kvtmp;
    const int Cout = isq ? 192 : 384;
    const int n0 = (isq ? blockIdx.y : blockIdx.y - 2) * 96;
    gemm1x1_body<96, 1>(A, Wr, 192, Cout, outp, nullptr, blockIdx.x, n0);
}

// ---------------- 3x3 full conv implicit GEMM, simple 2-barrier + XCD mt-swizzle ------
template <int BN, int EPI>
__global__ __launch_bounds__(256) void k_gemm3x3(const bf16* __restrict__ A,
                                                 const bf16* __restrict__ Wr,
                                                 const int Cin, const int Cout,
                                                 bf16* __restrict__ outp,
                                                 const char* __restrict__ zpage) {
    constexpr int WN = BN / 2, FN = WN / 16, BIT = BN / 32;
    __shared__ __align__(16) bf16 As[160 * 64];
    __shared__ __align__(16) bf16 Bs[BN * 64];
    const int t = threadIdx.x;
    const int mtRaw = blockIdx.x;
    const int mt = ((mtRaw & 7) << 5) | (mtRaw >> 3);   // XCD-contiguous rows
    const int n0 = blockIdx.y * BN;
    const int b = mt >> 7, y = mt & 127;
    const int w = t >> 6, lane = t & 63;
    const int wm = w >> 1, wn = w & 1;
    const int g = lane >> 4, r = lane & 15;
    const int ldw = t - lane;

    f32x4 acc[4][FN];
#pragma unroll
    for (int i = 0; i < 4; i++)
#pragma unroll
        for (int j = 0; j < FN; j++) acc[i][j] = {0.f, 0.f, 0.f, 0.f};

    for (int ky = 0; ky < 3; ky++) {
        const int yy = y + ky - 1;
        if (yy < 0 || yy > 127) continue;   // block-uniform
        const bf16* Ab = A + ((size_t)b * HW_ + (size_t)yy * 128) * Cin;
        for (int c0 = 0; c0 < Cin; c0 += 64) {
            for (int kx = 0; kx < 3; kx++) {
                if (kx == 0) {
#pragma unroll
                    for (int it = 0; it < 5; it++) {
                        int idx = it * 256 + t;
                        int row = idx >> 3, sl = idx & 7;
                        int so = (sl ^ (row & 7)) << 4;
                        const char* gp = (row >= 1 && row <= 128)
                            ? (const char*)(Ab + (size_t)(row - 1) * Cin + c0) + so
                            : zpage + so;
                        gl16(gp, (char*)As + (size_t)(it * 256 + ldw) * 16);
                    }
                }
                const bf16* Wb = Wr + (size_t)(ky * 3 + kx) * Cout * Cin;
#pragma unroll
                for (int it = 0; it < BIT; it++) {
                    int idx = it * 256 + t;
                    int row = idx >> 3, sl = idx & 7;
                    const char* gp = (const char*)(Wb + (size_t)(n0 + row) * Cin + c0) + ((sl ^ (row & 7)) << 4);
                    gl16(gp, (char*)Bs + (size_t)(it * 256 + ldw) * 16);
                }
                __syncthreads();
#pragma unroll
                for (int ks = 0; ks < 2; ks++) {
                    bf16x8v af[4], bv[FN];
#pragma unroll
                    for (int fm = 0; fm < 4; fm++)
                        af[fm] = lread(As, wm * 64 + fm * 16 + r + kx, ks * 4 + g);
#pragma unroll
                    for (int fn = 0; fn < FN; fn++)
                        bv[fn] = lread(Bs, wn * WN + fn * 16 + r, ks * 4 + g);
#pragma unroll
                    for (int fm = 0; fm < 4; fm++)
#pragma unroll
                        for (int fn = 0; fn < FN; fn++)
                            acc[fm][fn] = __builtin_amdgcn_mfma_f32_16x16x32_bf16(af[fm], bv[fn], acc[fm][fn], 0, 0, 0);
                }
                __syncthreads();
            }
        }
    }
#pragma unroll
    for (int fm = 0; fm < 4; fm++)
#pragma unroll
        for (int fn = 0; fn < FN; fn++)
#pragma unroll
            for (int reg = 0; reg < 4; reg++) {
                int xl = wm * 64 + fm * 16 + g * 4 + reg;
                int co = n0 + wn * WN + fn * 16 + r;
                float v = acc[fm][fn][reg];
                if constexpr (EPI == 1) v = 0.5f * v * (1.0f + erff(v * 0.70710678118654752f));
                outp[((size_t)mt * 128 + xl) * Cout + co] = tob(v);
            }
}

// ---------------- depthwise 3x3: sliding-window cols, 16 contiguous x per thread -------
__global__ __launch_bounds__(192) void k_dwconv2(const bf16* __restrict__ kv,
                                                 const float* __restrict__ wdw,
                                                 bf16* __restrict__ kout,
                                                 bf16* __restrict__ vout) {
    __shared__ float wlds[1728];
    const int t = threadIdx.x;
    const int row = blockIdx.x;
    const int z = blockIdx.y;
    const int b = row >> 7, y = row & 127;
    for (int i = t; i < 432; i += 192)
        ((float4*)wlds)[i] = ((const float4*)(wdw + (size_t)z * 1728))[i];
    __syncthreads();
    const int c8h = t % 24, xg = t / 24;
    const int cbase = z * C_ + c8h * 8;
    float wreg[9][8];
#pragma unroll
    for (int tap = 0; tap < 9; tap++)
#pragma unroll
        for (int j = 0; j < 8; j++) wreg[tap][j] = wlds[(c8h * 8 + j) * 9 + tap];

    bf16* outb = (z == 0 ? kout : vout) + (size_t)(b * HW_ + y * 128) * C_ + c8h * 8;
    const uint4 zero4 = make_uint4(0u, 0u, 0u, 0u);
    const int x0 = xg * 16;
    bool vy[3]; const bf16* rowp[3];
#pragma unroll
    for (int ky = 0; ky < 3; ky++) {
        int yy = y + ky - 1;
        vy[ky] = (yy >= 0 && yy <= 127);
        int yyc = vy[ky] ? yy : 0;
        rowp[ky] = kv + ((size_t)b * HW_ + (size_t)yyc * 128) * C2_ + cbase;
    }
    uint4 win[3][3];
#pragma unroll
    for (int ky = 0; ky < 3; ky++) {
        win[ky][0] = (vy[ky] && x0 - 1 >= 0) ? *(const uint4*)(rowp[ky] + (size_t)(x0 - 1) * C2_) : zero4;
        win[ky][1] = vy[ky] ? *(const uint4*)(rowp[ky] + (size_t)x0 * C2_) : zero4;
    }
    for (int i = 0; i < 16; i++) {
        int x = x0 + i;
#pragma unroll
        for (int ky = 0; ky < 3; ky++)
            win[ky][2] = (vy[ky] && x + 1 <= 127) ? *(const uint4*)(rowp[ky] + (size_t)(x + 1) * C2_) : zero4;
        float acc[8];
#pragma unroll
        for (int j = 0; j < 8; j++) acc[j] = 0.f;
#pragma unroll
        for (int ky = 0; ky < 3; ky++)
#pragma unroll
            for (int kx = 0; kx < 3; kx++) {
                const bf16* pv = (const bf16*)&win[ky][kx];
#pragma unroll
                for (int j = 0; j < 8; j++)
                    acc[j] += fb(pv[j]) * wreg[ky * 3 + kx][j];
            }
        union { bf16 h[8]; uint4 u; } ov;
#pragma unroll
        for (int j = 0; j < 8; j++) ov.h[j] = tob(acc[j]);
        *(uint4*)(outb + (size_t)x * C_) = ov.u;
#pragma unroll
        for (int ky = 0; ky < 3; ky++) { win[ky][0] = win[ky][1]; win[ky][1] = win[ky][2]; }
    }
}

// ---------------- S partials + fused ssq: per (b,hd,chunk) over 256 positions ----------
__global__ __launch_bounds__(256) void k_qk(const bf16* __restrict__ q,
                                            const bf16* __restrict__ k,
                                            float* __restrict__ Spart,
                                            float* __restrict__ ssq) {
    __shared__ float qs[64][49];
    __shared__ float ks[64][49];
    __shared__ float redq[4][48], redk[4][48];
    int t = threadIdx.x;
    int ch = blockIdx.x, hd = blockIdx.y, b = blockIdx.z;
    int i0 = (t >> 4) * 3, j0 = (t & 15) * 3;
    int cs = t % 48, qr = t / 48;
    float acc[3][3];
    float sq = 0.f, sk = 0.f;
#pragma unroll
    for (int a = 0; a < 3; a++)
#pragma unroll
        for (int c = 0; c < 3; c++) acc[a][c] = 0.f;

    for (int sub = 0; sub < 4; sub++) {
        size_t rbase = ((size_t)b * HW_ + ch * 256 + sub * 64) * C_ + hd * 48;
        for (int i = t; i < 64 * 6; i += 256) {
            int row = i / 6, oc = i % 6;
            uint4 v = *(const uint4*)(q + rbase + (size_t)row * C_ + oc * 8);
            const bf16* pv = (const bf16*)&v;
#pragma unroll
            for (int j = 0; j < 8; j++) qs[row][oc * 8 + j] = fb(pv[j]);
            uint4 v2 = *(const uint4*)(k + rbase + (size_t)row * C_ + oc * 8);
            const bf16* pv2 = (const bf16*)&v2;
#pragma unroll
            for (int j = 0; j < 8; j++) ks[row][oc * 8 + j] = fb(pv2[j]);
        }
        __syncthreads();
        if (t < 192) {
#pragma unroll
            for (int rr = 0; rr < 16; rr++) {
                float qv = qs[qr * 16 + rr][cs]; sq += qv * qv;
                float kv2 = ks[qr * 16 + rr][cs]; sk += kv2 * kv2;
            }
        }
        for (int p = 0; p < 64; p++) {
            float a0 = qs[p][i0], a1 = qs[p][i0 + 1], a2 = qs[p][i0 + 2];
            float b0 = ks[p][j0], b1 = ks[p][j0 + 1], b2 = ks[p][j0 + 2];
            acc[0][0] += a0 * b0; acc[0][1] += a0 * b1; acc[0][2] += a0 * b2;
            acc[1][0] += a1 * b0; acc[1][1] += a1 * b1; acc[1][2] += a1 * b2;
            acc[2][0] += a2 * b0; acc[2][1] += a2 * b1; acc[2][2] += a2 * b2;
        }
        __syncthreads();
    }
    if (t < 192) { redq[qr][cs] = sq; redk[qr][cs] = sk; }
    float* dst = Spart + (((size_t)(b * 4 + hd)) * 64 + ch) * 2304;
#pragma unroll
    for (int a = 0; a < 3; a++)
#pragma unroll
        for (int c = 0; c < 3; c++) dst[(i0 + a) * 48 + (j0 + c)] = acc[a][c];
    __syncthreads();
    if (t < 48) {
        float s0 = redq[0][t] + redq[1][t] + redq[2][t] + redq[3][t];
        float s1 = redk[0][t] + redk[1][t] + redk[2][t] + redk[3][t];
        ssq[((size_t)b * 64 + ch) * C_ + hd * 48 + t] = s0;
        ssq[((size_t)(2 + b) * 64 + ch) * C_ + hd * 48 + t] = s1;
    }
}

// ---------------- softmax: reduce 64 chunks, fused inv-norms, emit diag-block bf16 ----
__global__ __launch_bounds__(256) void k_softmax(const float* __restrict__ Spart,
                                                 const float* __restrict__ ssq,
                                                 const float* __restrict__ temp,
                                                 bf16* __restrict__ attnW) {
    __shared__ float S[2304];
    __shared__ float invk_s[48];
    int t = threadIdx.x;
    int hd = blockIdx.x, b = blockIdx.y;
    const float* base = Spart + ((size_t)(b * 4 + hd)) * 64 * 2304;
    for (int e = t; e < 2304; e += 256) {
        float s = 0.f;
        for (int ch = 0; ch < 64; ch++) s += base[(size_t)ch * 2304 + e];
        S[e] = s;
    }
    if (t < 48) {
        int c = hd * 48 + t;
        float sk = 0.f;
        for (int ch = 0; ch < 64; ch++) sk += ssq[((size_t)(2 + b) * 64 + ch) * C_ + c];
        invk_s[t] = 1.f / fmaxf(sqrtf(sk), 1e-12f);
    }
    __syncthreads();
    if (t >= 48) return;
    int c = hd * 48 + t;
    float sq = 0.f;
    for (int ch = 0; ch < 64; ch++) sq += ssq[((size_t)b * 64 + ch) * C_ + c];
    float qi = 1.f / fmaxf(sqrtf(sq), 1e-12f);
    float tp = temp[hd];
    float row[48];
    float mx = -1e30f;
    for (int j = 0; j < 48; j++) {
        float s = S[t * 48 + j] * qi * invk_s[j] * tp;
        row[j] = s;
        mx = fmaxf(mx, s);
    }
    float sum = 0.f;
    for (int j = 0; j < 48; j++) { row[j] = expf(row[j] - mx); sum += row[j]; }
    float is = 1.f / sum;
    bf16* wrow = attnW + ((size_t)b * 192 + hd * 48 + t) * 192 + hd * 48;
    for (int j = 0; j < 48; j++) wrow[j] = tob(row[j] * is);
}

// ---------------- M[b][c2][c0] = sum_{c1 in head(c0)} Wproj[c2][c1]*attn[b][c1][c0] ----
__global__ __launch_bounds__(256) void k_wav(const bf16* __restrict__ Wproj,
                                             const bf16* __restrict__ attnW,
                                             bf16* __restrict__ Mw) {
    int bid = blockIdx.x;
    int b = bid / 12, rg = bid % 12;
    int t = threadIdx.x;
    int row = rg * 16 + (t >> 4);
    int c0b = (t & 15) * 12;
    int hd = c0b / 48;
    const bf16* aw = attnW + (size_t)b * 36864;
    float acc[12];
#pragma unroll
    for (int j = 0; j < 12; j++) acc[j] = 0.f;
    for (int k = hd * 48; k < hd * 48 + 48; k++) {
        float wp = fb(Wproj[row * 192 + k]);
        const bf16* ar = aw + (size_t)k * 192 + c0b;
#pragma unroll
        for (int j = 0; j < 12; j++) acc[j] += wp * fb(ar[j]);
    }
    bf16* mrow = Mw + ((size_t)b * 192 + row) * 192 + c0b;
#pragma unroll
    for (int j = 0; j < 12; j++) mrow[j] = tob(acc[j]);
}

// =====================================================================================
extern "C" void kernel_launch(void* const* d_in, const int* in_sizes, int n_in,
                              void* d_out, int out_size, void* d_ws, size_t ws_size,
                              hipStream_t stream) {
    const float* x     = (const float*)d_in[0];
    const float* illum = (const float*)d_in[1];
    const float* ln1w  = (const float*)d_in[2];
    const float* ln1b  = (const float*)d_in[3];
    const float* lnLw  = (const float*)d_in[4];
    const float* lnLb  = (const float*)d_in[5];
    const float* ln2w  = (const float*)d_in[6];
    const float* ln2b  = (const float*)d_in[7];
    const float* qw    = (const float*)d_in[8];
    const float* qdww  = (const float*)d_in[9];
    const float* kvw   = (const float*)d_in[10];
    const float* kvdww = (const float*)d_in[11];
    const float* temp  = (const float*)d_in[12];
    const float* projw = (const float*)d_in[13];
    const float* pinw  = (const float*)d_in[14];
    const float* dww   = (const float*)d_in[15];
    const float* poutw = (const float*)d_in[16];

    char* ws = (char*)d_ws;
    bf16*  Wq1   = (bf16*)(ws + 0);
    bf16*  Wkv   = (bf16*)(ws + 73728);
    bf16*  Wqdw  = (bf16*)(ws + 221184);
    bf16*  Wproj = (bf16*)(ws + 884736);
    bf16*  Wpin  = (bf16*)(ws + 958464);
    bf16*  Wdw   = (bf16*)(ws + 1155072);
    bf16*  Wpout = (bf16*)(ws + 5873664);
    float* ssq   = (float*)(ws + 6070272);
    char*  zpage = (char*)(ws + 6266880);
    const size_t A0 = 6270976, u = 12582912;
    bf16* xn    = (bf16*)(ws + A0 + 0 * u);      // [LN1, qkv]
    bf16* iln   = (bf16*)(ws + A0 + 1 * u);      // [LNL, qkv]
    bf16* kvtmp = (bf16*)(ws + A0 + 2 * u);      // [qkv, dwconv] slots 2-3
    bf16* qtmp  = (bf16*)(ws + A0 + 4 * u);      // [qkv, q-3x3] slot4-lo
    bf16* qb    = (bf16*)(ws + A0 + 1 * u);      // [q-3x3, qk]
    bf16* kb    = (bf16*)(ws + A0 + 0 * u);      // [dwconv, qk] (xn dead after qkv)
    bf16* vb    = (bf16*)(ws + A0 + 4 * u + 12582912); // [dwconv, proj-gemm] slot4-hi
    float* Spart = (float*)(ws + A0 + 3 * u);          // [qk, softmax]
    bf16*  attnW = (bf16*)(ws + A0 + 3 * u + 4718592);
    bf16*  Mw    = (bf16*)(ws + A0 + 3 * u + 4866048);
    bf16* x2    = (bf16*)(ws + A0 + 0 * u);      // [proj, pout]
    bf16* xn2   = (bf16*)(ws + A0 + 3 * u);      // [LN2, pin]
    bf16* fbuf  = (bf16*)(ws + A0 + 4 * u);      // [pin, dw3x3] 33.5 MB
    bf16* gbuf  = (bf16*)(ws + A0 + 1 * u);      // [dw3x3, pout] 33.5 MB

    // 0) repacks + zpage + both NCHW LayerNorms, one launch
    k_repack_ln<<<3537, 256, 0, stream>>>(qw, kvw, projw, pinw, poutw, qdww, dww,
                                          Wq1, Wkv, Wproj, Wpin, Wpout, Wqdw, Wdw, zpage,
                                          x, illum, ln1w, ln1b, lnLw, lnLb, xn, iln);

    // 1) q-1x1 + kv-1x1 fused
    k_qkv<<<dim3(256, 6), 256, 0, stream>>>(iln, xn, Wq1, Wkv, qtmp, kvtmp);

    // 2) q full 3x3 -> qb ; kv depthwise -> kb, vb
    k_gemm3x3<96, 0><<<dim3(256, 2), 256, 0, stream>>>(qtmp, Wqdw, 192, 192, qb, zpage);
    k_dwconv2<<<dim3(256, 2), 192, 0, stream>>>(kvtmp, kvdww, kb, vb);

    // 3) attention
    k_qk<<<dim3(64, 4, 2), 256, 0, stream>>>(qb, kb, Spart, ssq);
    k_softmax<<<dim3(4, 2), 256, 0, stream>>>(Spart, ssq, temp, attnW);
    k_wav<<<24, 256, 0, stream>>>(Wproj, attnW, Mw);

    // 4) x2 = x + v @ (proj∘attn)
    k_gemm1x1<96, 2><<<dim3(256, 2), 256, 0, stream>>>(vb, Mw, 192, 192, x2, x, 36864);

    // 5) FFN
    k_ln_pc<<<512, 256, 0, stream>>>(x2, ln2w, ln2b, xn2);
    k_gemm1x1<128, 1><<<dim3(256, 4), 256, 0, stream>>>(xn2, Wpin, 192, 512, fbuf, nullptr, 0);
    k_gemm3x3<128, 1><<<dim3(256, 4), 256, 0, stream>>>(fbuf, Wdw, 512, 512, gbuf, zpage);
    k_gemm1x1<96, 3><<<dim3(256, 2), 256, 0, stream>>>(gbuf, Wpout, 512, 192, d_out, x2, 0);
}